// Round 1
// baseline (505.906 us; speedup 1.0000x reference)
//
#include <hip/hip_runtime.h>

// Problem: B=32, L=512, D=1024, 7 linear experts + identity, routed per token.
// out[t] = (type[t]==0) ? actions[t] : W[type[t]-1] @ actions[t] + b[type[t]-1]
//
// Strategy: bucket tokens by expert type (atomic scatter into d_ws lists),
// copy identity rows, then one gathered fp32 GEMM per expert:
//   (n_k x 1024) x (1024 x 1024)^T, tile 128x128x32, 8x8 per-thread.

#define NTOK (32 * 512)   // 16384 tokens
#define DDIM 1024
#define NEXP 7
#define BM 128
#define BN 128
#define BK 32
#define TM 8
#define TN 8
#define LDA (BM + 4)      // pad to break power-of-2 bank stride

__global__ void zero_counts_k(int* counts) {
    if (threadIdx.x < 8) counts[threadIdx.x] = 0;
}

__global__ void bucket_k(const int* __restrict__ type, int* __restrict__ counts,
                         int* __restrict__ lists) {
    int t = blockIdx.x * blockDim.x + threadIdx.x;
    if (t >= NTOK) return;
    int k = type[t];
    if (k > 0) {
        int pos = atomicAdd(&counts[k], 1);
        lists[(k - 1) * NTOK + pos] = t;
    }
}

// Identity expert: out row = input row for type==0 tokens.
__global__ void copy_identity_k(const float4* __restrict__ A,
                                const int* __restrict__ type,
                                float4* __restrict__ out) {
    int t = blockIdx.x;
    if (type[t] != 0) return;
    const int nv = DDIM / 4;  // 256 float4 per row
    for (int i = threadIdx.x; i < nv; i += 64)
        out[(size_t)t * nv + i] = A[(size_t)t * nv + i];
}

__global__ __launch_bounds__(256) void gemm_expert_k(
    const float* __restrict__ A,      // (16384, 1024) actions
    const float* __restrict__ W,      // (7, 1024, 1024) row-major (out, in)
    const float* __restrict__ bias,   // (7, 1024)
    float* __restrict__ out,          // (16384, 1024)
    const int* __restrict__ counts,   // [8]
    const int* __restrict__ lists)    // [7][16384]
{
    const int e = blockIdx.z;              // expert 0..6 (type e+1)
    const int n = counts[e + 1];
    const int row0 = blockIdx.y * BM;
    if (row0 >= n) return;                 // empty tile -> exit
    const int col0 = blockIdx.x * BN;
    const int* lst = lists + e * NTOK;

    __shared__ float As[BK][LDA];          // K-major (transposed on store)
    __shared__ float Ws[BK][LDA];

    const int tid = threadIdx.x;
    const int tx = tid & 15, ty = tid >> 4;

    // staging coords: 8 threads per row, 32 rows per pass, 4 passes
    const int sr = tid >> 3;               // 0..31
    const int sc = (tid & 7) * 4;          // 0,4,...,28

    int toks[4];
#pragma unroll
    for (int p = 0; p < 4; ++p) {
        int gr = row0 + p * 32 + sr;
        toks[p] = lst[min(gr, n - 1)];     // clamp for partial tiles
    }
    const float* Wb = W + (size_t)e * DDIM * DDIM;

    float acc[TM][TN];
#pragma unroll
    for (int i = 0; i < TM; ++i)
#pragma unroll
        for (int j = 0; j < TN; ++j) acc[i][j] = 0.f;

    for (int k0 = 0; k0 < DDIM; k0 += BK) {
        __syncthreads();
#pragma unroll
        for (int p = 0; p < 4; ++p) {
            int r = p * 32 + sr;
            float4 va = *(const float4*)&A[(size_t)toks[p] * DDIM + k0 + sc];
            As[sc + 0][r] = va.x; As[sc + 1][r] = va.y;
            As[sc + 2][r] = va.z; As[sc + 3][r] = va.w;
            float4 vw = *(const float4*)&Wb[(size_t)(col0 + r) * DDIM + k0 + sc];
            Ws[sc + 0][r] = vw.x; Ws[sc + 1][r] = vw.y;
            Ws[sc + 2][r] = vw.z; Ws[sc + 3][r] = vw.w;
        }
        __syncthreads();
#pragma unroll
        for (int kk = 0; kk < BK; ++kk) {
            float a[TM], w[TN];
            *(float4*)&a[0] = *(const float4*)&As[kk][ty * 8 + 0];
            *(float4*)&a[4] = *(const float4*)&As[kk][ty * 8 + 4];
            *(float4*)&w[0] = *(const float4*)&Ws[kk][tx * 8 + 0];
            *(float4*)&w[4] = *(const float4*)&Ws[kk][tx * 8 + 4];
#pragma unroll
            for (int i = 0; i < TM; ++i)
#pragma unroll
                for (int j = 0; j < TN; ++j)
                    acc[i][j] = fmaf(a[i], w[j], acc[i][j]);
        }
    }

    float bs[TN];
#pragma unroll
    for (int j = 0; j < TN; ++j) bs[j] = bias[e * DDIM + col0 + tx * 8 + j];

#pragma unroll
    for (int i = 0; i < TM; ++i) {
        int gr = row0 + ty * 8 + i;
        if (gr < n) {
            int tok = lst[gr];
#pragma unroll
            for (int j4 = 0; j4 < TN; j4 += 4) {
                float4 v = { acc[i][j4 + 0] + bs[j4 + 0],
                             acc[i][j4 + 1] + bs[j4 + 1],
                             acc[i][j4 + 2] + bs[j4 + 2],
                             acc[i][j4 + 3] + bs[j4 + 3] };
                *(float4*)&out[(size_t)tok * DDIM + col0 + tx * 8 + j4] = v;
            }
        }
    }
}

extern "C" void kernel_launch(void* const* d_in, const int* in_sizes, int n_in,
                              void* d_out, int out_size, void* d_ws, size_t ws_size,
                              hipStream_t stream) {
    const float* actions = (const float*)d_in[0];   // (32,512,1024) f32
    const int*   atype   = (const int*)d_in[1];     // (32,512) i32
    const float* W       = (const float*)d_in[2];   // (7,1024,1024) f32
    const float* bias    = (const float*)d_in[3];   // (7,1024) f32
    float* out = (float*)d_out;

    int* counts = (int*)d_ws;                        // 8 ints
    int* lists  = (int*)((char*)d_ws + 256);         // 7 * 16384 ints

    zero_counts_k<<<1, 64, 0, stream>>>(counts);
    bucket_k<<<NTOK / 256, 256, 0, stream>>>(atype, counts, lists);
    copy_identity_k<<<NTOK, 64, 0, stream>>>((const float4*)actions, atype,
                                             (float4*)out);
    dim3 grid(DDIM / BN, NTOK / BM, NEXP);
    gemm_expert_k<<<grid, 256, 0, stream>>>(actions, W, bias, out, counts, lists);
}

// Round 2
// 173.633 us; speedup vs baseline: 2.9137x; 2.9137x over previous
//
#include <hip/hip_runtime.h>

// B=32, L=512, D=1024; 7 linear experts + identity, routed per token.
// out[t] = (type[t]==0) ? actions[t] : W[type[t]-1] @ actions[t] + b
//
// Bucket tokens by expert, copy identity rows, then one gathered bf16-MFMA
// GEMM per expert: tile 128x128, BK=64, 4 waves x (4x4 frags of 16x16x32).
// f32 inputs converted to bf16 (RNE) during LDS staging.

#define NTOK 16384
#define DDIM 1024
#define NEXP 7
#define BM 128
#define BN 128
#define BK 64
#define LDK 72   // padded LDS k-stride (shorts): 144B row stride -> 2-way bank alias (free)

typedef __attribute__((ext_vector_type(8))) short short8;
typedef __attribute__((ext_vector_type(4))) float f32x4;

__device__ __forceinline__ unsigned short f2bf(float f) {
    unsigned u = __float_as_uint(f);
    u += 0x7fff + ((u >> 16) & 1);   // round-to-nearest-even
    return (unsigned short)(u >> 16);
}

__global__ void zero_counts_k(int* counts) {
    if (threadIdx.x < 8) counts[threadIdx.x] = 0;
}

__global__ void bucket_k(const int* __restrict__ type, int* __restrict__ counts,
                         int* __restrict__ lists) {
    int t = blockIdx.x * blockDim.x + threadIdx.x;
    if (t >= NTOK) return;
    int k = type[t];
    if (k > 0) {
        int pos = atomicAdd(&counts[k], 1);
        lists[(k - 1) * NTOK + pos] = t;
    }
}

__global__ __launch_bounds__(256) void copy_identity_k(
    const float4* __restrict__ A, const int* __restrict__ type,
    float4* __restrict__ out) {
    int t = blockIdx.x;
    if (type[t] != 0) return;
    out[(size_t)t * 256 + threadIdx.x] = A[(size_t)t * 256 + threadIdx.x];
}

__global__ __launch_bounds__(256) void gemm_expert_k(
    const float* __restrict__ A,      // (16384, 1024)
    const float* __restrict__ W,      // (7, 1024, 1024) (out, in)
    const float* __restrict__ bias,   // (7, 1024)
    float* __restrict__ out,          // (16384, 1024)
    const int* __restrict__ counts,   // [8]
    const int* __restrict__ lists)    // [7][16384]
{
    const int e = blockIdx.z;
    const int n = counts[e + 1];
    const int row0 = blockIdx.y * BM;
    if (row0 >= n) return;
    const int col0 = blockIdx.x * BN;
    const int* lst = lists + e * NTOK;
    const float* Wb = W + (size_t)e * DDIM * DDIM;

    __shared__ unsigned short As[BM][LDK];   // [row][k] bf16
    __shared__ unsigned short Bs[BN][LDK];   // [col][k] bf16

    const int tid  = threadIdx.x;
    const int lane = tid & 63;
    const int wave = tid >> 6;
    const int wr = wave >> 1, wc = wave & 1;   // wave -> 64x64 quadrant

    // staging: 4 threads per row (each 16 f32 of k), 64 rows/pass, 2 passes
    const int srow = tid >> 2;   // 0..63
    const int sq   = tid & 3;    // k-quarter

    const float* asrc[2];
#pragma unroll
    for (int p = 0; p < 2; ++p) {
        int gr = row0 + p * 64 + srow;
        asrc[p] = A + (size_t)lst[min(gr, n - 1)] * DDIM + sq * 16;
    }
    const float* bsrc[2];
#pragma unroll
    for (int p = 0; p < 2; ++p)
        bsrc[p] = Wb + (size_t)(col0 + p * 64 + srow) * DDIM + sq * 16;

    f32x4 acc[4][4];
#pragma unroll
    for (int m = 0; m < 4; ++m)
#pragma unroll
        for (int nn = 0; nn < 4; ++nn) acc[m][nn] = (f32x4){0.f, 0.f, 0.f, 0.f};

    for (int k0 = 0; k0 < DDIM; k0 += BK) {
        // ---- stage A and B (f32 -> bf16) ----
#pragma unroll
        for (int p = 0; p < 2; ++p) {
            float4 v[4];
#pragma unroll
            for (int j = 0; j < 4; ++j)
                v[j] = *(const float4*)(asrc[p] + k0 + j * 4);
            short8 h0, h1;
#pragma unroll
            for (int j = 0; j < 2; ++j) {
                h0[j * 4 + 0] = f2bf(v[j].x); h0[j * 4 + 1] = f2bf(v[j].y);
                h0[j * 4 + 2] = f2bf(v[j].z); h0[j * 4 + 3] = f2bf(v[j].w);
            }
#pragma unroll
            for (int j = 0; j < 2; ++j) {
                h1[j * 4 + 0] = f2bf(v[2 + j].x); h1[j * 4 + 1] = f2bf(v[2 + j].y);
                h1[j * 4 + 2] = f2bf(v[2 + j].z); h1[j * 4 + 3] = f2bf(v[2 + j].w);
            }
            *(short8*)&As[p * 64 + srow][sq * 16 + 0] = h0;
            *(short8*)&As[p * 64 + srow][sq * 16 + 8] = h1;
        }
#pragma unroll
        for (int p = 0; p < 2; ++p) {
            float4 v[4];
#pragma unroll
            for (int j = 0; j < 4; ++j)
                v[j] = *(const float4*)(bsrc[p] + k0 + j * 4);
            short8 h0, h1;
#pragma unroll
            for (int j = 0; j < 2; ++j) {
                h0[j * 4 + 0] = f2bf(v[j].x); h0[j * 4 + 1] = f2bf(v[j].y);
                h0[j * 4 + 2] = f2bf(v[j].z); h0[j * 4 + 3] = f2bf(v[j].w);
            }
#pragma unroll
            for (int j = 0; j < 2; ++j) {
                h1[j * 4 + 0] = f2bf(v[2 + j].x); h1[j * 4 + 1] = f2bf(v[2 + j].y);
                h1[j * 4 + 2] = f2bf(v[2 + j].z); h1[j * 4 + 3] = f2bf(v[2 + j].w);
            }
            *(short8*)&Bs[p * 64 + srow][sq * 16 + 0] = h0;
            *(short8*)&Bs[p * 64 + srow][sq * 16 + 8] = h1;
        }
        __syncthreads();

        // ---- MFMA: 2 k-subs of 32, 4x4 fragments of 16x16 ----
#pragma unroll
        for (int ks = 0; ks < 2; ++ks) {
            const int ko = ks * 32 + (lane >> 4) * 8;
            short8 af[4], bf[4];
#pragma unroll
            for (int m = 0; m < 4; ++m)
                af[m] = *(const short8*)&As[wr * 64 + m * 16 + (lane & 15)][ko];
#pragma unroll
            for (int nn = 0; nn < 4; ++nn)
                bf[nn] = *(const short8*)&Bs[wc * 64 + nn * 16 + (lane & 15)][ko];
#pragma unroll
            for (int m = 0; m < 4; ++m)
#pragma unroll
                for (int nn = 0; nn < 4; ++nn)
                    acc[m][nn] = __builtin_amdgcn_mfma_f32_16x16x32_bf16(
                        af[m], bf[nn], acc[m][nn], 0, 0, 0);
        }
        __syncthreads();
    }

    // ---- epilogue: bias + gathered store ----
    const int ccol  = lane & 15;
    const int crow4 = (lane >> 4) * 4;
    float bv[4];
#pragma unroll
    for (int nn = 0; nn < 4; ++nn)
        bv[nn] = bias[e * DDIM + col0 + wc * 64 + nn * 16 + ccol];

#pragma unroll
    for (int m = 0; m < 4; ++m) {
#pragma unroll
        for (int r = 0; r < 4; ++r) {
            int gr = row0 + wr * 64 + m * 16 + crow4 + r;
            if (gr >= n) continue;
            int tok = lst[gr];
            float* orow = out + (size_t)tok * DDIM + col0 + wc * 64 + ccol;
#pragma unroll
            for (int nn = 0; nn < 4; ++nn)
                orow[nn * 16] = acc[m][nn][r] + bv[nn];
        }
    }
}

extern "C" void kernel_launch(void* const* d_in, const int* in_sizes, int n_in,
                              void* d_out, int out_size, void* d_ws, size_t ws_size,
                              hipStream_t stream) {
    const float* actions = (const float*)d_in[0];
    const int*   atype   = (const int*)d_in[1];
    const float* W       = (const float*)d_in[2];
    const float* bias    = (const float*)d_in[3];
    float* out = (float*)d_out;

    int* counts = (int*)d_ws;
    int* lists  = (int*)((char*)d_ws + 256);

    zero_counts_k<<<1, 64, 0, stream>>>(counts);
    bucket_k<<<NTOK / 256, 256, 0, stream>>>(atype, counts, lists);
    copy_identity_k<<<NTOK, 256, 0, stream>>>((const float4*)actions, atype,
                                              (float4*)out);
    dim3 grid(DDIM / BN, NTOK / BM, NEXP);
    gemm_expert_k<<<grid, 256, 0, stream>>>(actions, W, bias, out, counts, lists);
}

// Round 3
// 162.561 us; speedup vs baseline: 3.1121x; 1.0681x over previous
//
#include <hip/hip_runtime.h>

// B=32, L=512, D=1024; 7 linear experts + identity, routed per token.
// Pipeline: bucket -> offsets/tile-table -> convert W to bf16, gather+convert
// routed A rows to bf16 (compacted per expert), copy identity rows ->
// m97-style bf16 MFMA GEMM (global_load_lds staging, 128x128 tile, BK=64).

#define NTOK 16384
#define DDIM 1024
#define NEXP 7
#define BM 128
#define BN 128
#define BK 64

// workspace layout (bytes); total ~47 MB
#define WS_OFFS_I   16          // int index of offs[8]
#define WS_NTILES_I 32          // int index of ntiles
#define WS_TABLE_I  64          // int index of tile table (160 x {expert,row0})
#define WS_CTOK_B   2048        // compact slot -> token  (16384 int)
#define WS_LISTS_B  67584       // 7 * 16384 int
#define WS_ABF_B    1048576     // 16384*1024 bf16 = 32 MB
#define WS_WBF_B    34603008    // 7*1024*1024 bf16 = 14 MB (end 49283072)

typedef __attribute__((ext_vector_type(8))) short short8;
typedef __attribute__((ext_vector_type(4))) float f32x4;

__device__ __forceinline__ unsigned short f2bf(float f) {
    unsigned u = __float_as_uint(f);
    u += 0x7fff + ((u >> 16) & 1);
    return (unsigned short)(u >> 16);
}

__device__ __forceinline__ void gload16(const void* g, void* l) {
    __builtin_amdgcn_global_load_lds(
        (const __attribute__((address_space(1))) void*)g,
        (__attribute__((address_space(3))) void*)l, 16, 0, 0);
}

__global__ void zero_counts_k(int* counts) {
    if (threadIdx.x < 8) counts[threadIdx.x] = 0;
}

__global__ void bucket_k(const int* __restrict__ type, int* __restrict__ counts,
                         int* __restrict__ lists) {
    int t = blockIdx.x * 256 + threadIdx.x;
    int k = type[t];
    if (k > 0) {
        int pos = atomicAdd(&counts[k], 1);
        lists[(k - 1) * NTOK + pos] = t;
    }
}

__global__ void offsets_k(int* wsi) {
    if (threadIdx.x != 0) return;
    int* counts = wsi;
    int* offs   = wsi + WS_OFFS_I;
    int* table  = wsi + WS_TABLE_I;
    int acc = 0, t = 0;
    for (int e = 0; e < NEXP; ++e) {
        offs[e] = acc;
        int c = counts[e + 1];
        int nt = (c + BM - 1) / BM;
        for (int i = 0; i < nt; ++i) {
            table[2 * t] = e; table[2 * t + 1] = acc + i * BM; ++t;
        }
        acc += c;
    }
    offs[NEXP] = acc;
    wsi[WS_NTILES_I] = t;
}

// Gather routed rows, convert f32->bf16, write compacted (one 64-lane group/row).
__global__ __launch_bounds__(256) void convertA_k(
    const float* __restrict__ A, const int* __restrict__ wsi,
    const int* __restrict__ lists, int* __restrict__ ctok,
    unsigned short* __restrict__ Abf) {
    const int* offs = wsi + WS_OFFS_I;
    int s = blockIdx.x * 4 + (threadIdx.x >> 6);
    if (s >= offs[NEXP]) return;
    int lane = threadIdx.x & 63;
    int e = 0;
    while (s >= offs[e + 1]) ++e;
    int tok = lists[e * NTOK + (s - offs[e])];
    if (lane == 0) ctok[s] = tok;
    const float4* src = (const float4*)(A + (size_t)tok * DDIM) + lane * 4;
    float4 v0 = src[0], v1 = src[1], v2 = src[2], v3 = src[3];
    short8 h0, h1;
    h0[0]=f2bf(v0.x); h0[1]=f2bf(v0.y); h0[2]=f2bf(v0.z); h0[3]=f2bf(v0.w);
    h0[4]=f2bf(v1.x); h0[5]=f2bf(v1.y); h0[6]=f2bf(v1.z); h0[7]=f2bf(v1.w);
    h1[0]=f2bf(v2.x); h1[1]=f2bf(v2.y); h1[2]=f2bf(v2.z); h1[3]=f2bf(v2.w);
    h1[4]=f2bf(v3.x); h1[5]=f2bf(v3.y); h1[6]=f2bf(v3.z); h1[7]=f2bf(v3.w);
    unsigned short* d = Abf + (size_t)s * DDIM + lane * 16;
    *(short8*)d = h0;
    *(short8*)(d + 8) = h1;
}

__global__ __launch_bounds__(256) void identity_k(
    const float4* __restrict__ A, const int* __restrict__ type,
    float4* __restrict__ out) {
    int t = blockIdx.x * 4 + (threadIdx.x >> 6);
    if (type[t] != 0) return;
    int lane = threadIdx.x & 63;
    const float4* s = A + (size_t)t * 256;
    float4* d = out + (size_t)t * 256;
#pragma unroll
    for (int j = 0; j < 4; ++j) d[lane + j * 64] = s[lane + j * 64];
}

__global__ __launch_bounds__(256) void convertW_k(
    const float* __restrict__ W, unsigned short* __restrict__ Wbf) {
    size_t i = ((size_t)blockIdx.x * 256 + threadIdx.x) * 16;
    const float4* src = (const float4*)(W + i);
    float4 v0 = src[0], v1 = src[1], v2 = src[2], v3 = src[3];
    short8 h0, h1;
    h0[0]=f2bf(v0.x); h0[1]=f2bf(v0.y); h0[2]=f2bf(v0.z); h0[3]=f2bf(v0.w);
    h0[4]=f2bf(v1.x); h0[5]=f2bf(v1.y); h0[6]=f2bf(v1.z); h0[7]=f2bf(v1.w);
    h1[0]=f2bf(v2.x); h1[1]=f2bf(v2.y); h1[2]=f2bf(v2.z); h1[3]=f2bf(v2.w);
    h1[4]=f2bf(v3.x); h1[5]=f2bf(v3.y); h1[6]=f2bf(v3.z); h1[7]=f2bf(v3.w);
    *(short8*)(Wbf + i) = h0;
    *(short8*)(Wbf + i + 8) = h1;
}

__global__ __launch_bounds__(256) void gemm_k(
    const unsigned short* __restrict__ Abf,
    const unsigned short* __restrict__ Wbf,
    const float* __restrict__ bias, float* __restrict__ out,
    const int* __restrict__ wsi, const int* __restrict__ ctok) {
    const int ntiles = wsi[WS_NTILES_I];
    const int ty = blockIdx.y;
    if (ty >= ntiles) return;
    const int* offs = wsi + WS_OFFS_I;
    const int* tab  = wsi + WS_TABLE_I;
    const int e     = tab[2 * ty];
    const int crow0 = tab[2 * ty + 1];
    const int nend  = offs[e + 1];
    const int col0  = blockIdx.x * BN;

    __shared__ unsigned short As[BM * BK];   // linear [row][k], 16 KB
    __shared__ unsigned short Bs[BN * BK];

    const int tid = threadIdx.x, lane = tid & 63, wave = tid >> 6;
    const int wr = wave >> 1, wc = wave & 1;
    const int srow = tid >> 3;          // 0..31 (row within 32-row pass)
    const int skc  = (tid & 7) * 8;     // k element offset

    const unsigned short* Wb = Wbf + (size_t)e * DDIM * DDIM;

    f32x4 acc[4][4];
#pragma unroll
    for (int m = 0; m < 4; ++m)
#pragma unroll
        for (int nn = 0; nn < 4; ++nn) acc[m][nn] = (f32x4){0.f, 0.f, 0.f, 0.f};

    for (int k0 = 0; k0 < DDIM; k0 += BK) {
#pragma unroll
        for (int p = 0; p < 4; ++p) {
            int r = p * 32 + srow;
            gload16(Abf + (size_t)(crow0 + r) * DDIM + k0 + skc,
                    (char*)As + p * 4096 + wave * 1024);
        }
#pragma unroll
        for (int p = 0; p < 4; ++p) {
            int r = p * 32 + srow;
            gload16(Wb + (size_t)(col0 + r) * DDIM + k0 + skc,
                    (char*)Bs + p * 4096 + wave * 1024);
        }
        __syncthreads();
#pragma unroll
        for (int ks = 0; ks < 2; ++ks) {
            const int ko = ks * 32 + (lane >> 4) * 8;
            short8 af[4], bf[4];
#pragma unroll
            for (int m = 0; m < 4; ++m)
                af[m] = *(const short8*)&As[(wr * 64 + m * 16 + (lane & 15)) * BK + ko];
#pragma unroll
            for (int nn = 0; nn < 4; ++nn)
                bf[nn] = *(const short8*)&Bs[(wc * 64 + nn * 16 + (lane & 15)) * BK + ko];
#pragma unroll
            for (int m = 0; m < 4; ++m)
#pragma unroll
                for (int nn = 0; nn < 4; ++nn)
                    acc[m][nn] = __builtin_amdgcn_mfma_f32_16x16x32_bf16(
                        af[m], bf[nn], acc[m][nn], 0, 0, 0);
        }
        __syncthreads();
    }

    const int ccol  = lane & 15;
    const int crow4 = (lane >> 4) * 4;
    float bv[4];
#pragma unroll
    for (int nn = 0; nn < 4; ++nn)
        bv[nn] = bias[e * DDIM + col0 + wc * 64 + nn * 16 + ccol];

#pragma unroll
    for (int m = 0; m < 4; ++m) {
#pragma unroll
        for (int r = 0; r < 4; ++r) {
            int gr = crow0 + wr * 64 + m * 16 + crow4 + r;
            if (gr >= nend) continue;
            int tok = ctok[gr];
            float* orow = out + (size_t)tok * DDIM + col0 + wc * 64 + ccol;
#pragma unroll
            for (int nn = 0; nn < 4; ++nn)
                orow[nn * 16] = acc[m][nn][r] + bv[nn];
        }
    }
}

extern "C" void kernel_launch(void* const* d_in, const int* in_sizes, int n_in,
                              void* d_out, int out_size, void* d_ws, size_t ws_size,
                              hipStream_t stream) {
    const float* actions = (const float*)d_in[0];
    const int*   atype   = (const int*)d_in[1];
    const float* W       = (const float*)d_in[2];
    const float* bias    = (const float*)d_in[3];
    float* out = (float*)d_out;

    int* wsi = (int*)d_ws;
    int* ctok  = wsi + WS_CTOK_B / 4;
    int* lists = wsi + WS_LISTS_B / 4;
    unsigned short* Abf = (unsigned short*)((char*)d_ws + WS_ABF_B);
    unsigned short* Wbf = (unsigned short*)((char*)d_ws + WS_WBF_B);

    zero_counts_k<<<1, 64, 0, stream>>>(wsi);
    convertW_k<<<1792, 256, 0, stream>>>(W, Wbf);
    bucket_k<<<NTOK / 256, 256, 0, stream>>>(atype, wsi, lists);
    offsets_k<<<1, 64, 0, stream>>>(wsi);
    convertA_k<<<NTOK / 4, 256, 0, stream>>>(actions, wsi, lists, ctok, Abf);
    identity_k<<<NTOK / 4, 256, 0, stream>>>((const float4*)actions, atype,
                                             (float4*)out);
    dim3 grid(DDIM / BN, 136);
    gemm_k<<<grid, 256, 0, stream>>>(Abf, Wbf, bias, out, wsi, ctok);
}

// Round 4
// 102.331 us; speedup vs baseline: 4.9438x; 1.5886x over previous
//
#include <hip/hip_runtime.h>

// B=32, L=512, D=1024; 7 linear experts + identity, routed per token.
// Pipeline: count (LDS hist) -> offsets/tile-table -> slot-assign ->
// rowconv (gather+f32->bf16 compact OR identity copy) + convertW ->
// m97-style bf16 MFMA GEMM (global_load_lds, 128x128 tile, BK=64,
// XCD-chunked block mapping for A-tile L2 reuse).

#define NTOK 16384
#define DDIM 1024
#define NEXP 7
#define BM 128
#define BN 128
#define BK 64
#define MAXTILES 136          // = 8 XCDs * 17

// ws layout (int indices / byte offsets)
#define WI_COUNTS 0           // [8]
#define WI_CURS   8           // [8]
#define WI_OFFS   16          // [8] compact start per expert; offs[7]=total
#define WI_NTILES 32
#define WI_TABLE  64          // [136][2] {expert, crow0}
#define WI_CTOK   512         // [16384] slot -> token
#define WI_SMAP   (512 + 16384) // [16384] token -> slot (-1 = identity)
#define WS_ABF_B  1048576                       // 32 MB bf16 A (compact)
#define WS_WBF_B  (WS_ABF_B + NTOK * DDIM * 2)  // 14 MB bf16 W

typedef __attribute__((ext_vector_type(8))) short short8;
typedef __attribute__((ext_vector_type(4))) float f32x4;

__device__ __forceinline__ unsigned short f2bf(float f) {
    unsigned u = __float_as_uint(f);
    u += 0x7fff + ((u >> 16) & 1);
    return (unsigned short)(u >> 16);
}

__device__ __forceinline__ void gload16(const void* g, void* l) {
    __builtin_amdgcn_global_load_lds(
        (const __attribute__((address_space(1))) void*)g,
        (__attribute__((address_space(3))) void*)l, 16, 0, 0);
}

__global__ __launch_bounds__(1024) void count_k(
    const int* __restrict__ type, int* __restrict__ wsi) {
    __shared__ int lh[8];
    int tid = threadIdx.x;
    if (tid < 8) lh[tid] = 0;
    __syncthreads();
    int k = type[blockIdx.x * 1024 + tid];
    if (k > 0) atomicAdd(&lh[k], 1);
    __syncthreads();
    if (tid >= 1 && tid < 8) atomicAdd(&wsi[WI_COUNTS + tid], lh[tid]);
}

__global__ void offsets_k(int* wsi) {
    if (threadIdx.x != 0) return;
    const int* counts = wsi + WI_COUNTS;
    int* offs  = wsi + WI_OFFS;
    int* curs  = wsi + WI_CURS;
    int* table = wsi + WI_TABLE;
    int acc = 0, t = 0;
    for (int e = 0; e < NEXP; ++e) {
        offs[e] = acc;
        curs[e + 1] = acc;
        int c = counts[e + 1];
        int nt = (c + BM - 1) / BM;
        for (int i = 0; i < nt; ++i) {
            table[2 * t] = e; table[2 * t + 1] = acc + i * BM; ++t;
        }
        acc += c;
    }
    offs[NEXP] = acc;
    wsi[WI_NTILES] = t;
}

__global__ __launch_bounds__(1024) void slot_k(
    const int* __restrict__ type, int* __restrict__ wsi) {
    __shared__ int lh[8], lbase[8];
    int tid = threadIdx.x;
    if (tid < 8) lh[tid] = 0;
    __syncthreads();
    int t = blockIdx.x * 1024 + tid;
    int k = type[t];
    int lpos = 0;
    if (k > 0) lpos = atomicAdd(&lh[k], 1);
    __syncthreads();
    if (tid >= 1 && tid < 8) lbase[tid] = atomicAdd(&wsi[WI_CURS + tid], lh[tid]);
    __syncthreads();
    int s = -1;
    if (k > 0) { s = lbase[k] + lpos; wsi[WI_CTOK + s] = t; }
    wsi[WI_SMAP + t] = s;
}

// One wave per token row: identity copy (f32->out) or gather+convert (bf16->Abf).
__global__ __launch_bounds__(256) void rowconv_k(
    const float* __restrict__ A, const int* __restrict__ wsi,
    unsigned short* __restrict__ Abf, float* __restrict__ out) {
    int wave = threadIdx.x >> 6, lane = threadIdx.x & 63;
    int t = blockIdx.x * 4 + wave;
    int s = wsi[WI_SMAP + t];
    const float4* src = (const float4*)(A + (size_t)t * DDIM);
    if (s < 0) {
        float4* d = (float4*)(out + (size_t)t * DDIM);
#pragma unroll
        for (int j = 0; j < 4; ++j) d[lane + j * 64] = src[lane + j * 64];
    } else {
        float4 v0 = src[lane * 4 + 0], v1 = src[lane * 4 + 1];
        float4 v2 = src[lane * 4 + 2], v3 = src[lane * 4 + 3];
        short8 h0, h1;
        h0[0]=f2bf(v0.x); h0[1]=f2bf(v0.y); h0[2]=f2bf(v0.z); h0[3]=f2bf(v0.w);
        h0[4]=f2bf(v1.x); h0[5]=f2bf(v1.y); h0[6]=f2bf(v1.z); h0[7]=f2bf(v1.w);
        h1[0]=f2bf(v2.x); h1[1]=f2bf(v2.y); h1[2]=f2bf(v2.z); h1[3]=f2bf(v2.w);
        h1[4]=f2bf(v3.x); h1[5]=f2bf(v3.y); h1[6]=f2bf(v3.z); h1[7]=f2bf(v3.w);
        unsigned short* d = Abf + (size_t)s * DDIM + lane * 16;
        *(short8*)d = h0;
        *(short8*)(d + 8) = h1;
    }
}

__global__ __launch_bounds__(256) void convertW_k(
    const float* __restrict__ W, unsigned short* __restrict__ Wbf) {
    size_t i = ((size_t)blockIdx.x * 256 + threadIdx.x) * 16;
    const float4* src = (const float4*)(W + i);
    float4 v0 = src[0], v1 = src[1], v2 = src[2], v3 = src[3];
    short8 h0, h1;
    h0[0]=f2bf(v0.x); h0[1]=f2bf(v0.y); h0[2]=f2bf(v0.z); h0[3]=f2bf(v0.w);
    h0[4]=f2bf(v1.x); h0[5]=f2bf(v1.y); h0[6]=f2bf(v1.z); h0[7]=f2bf(v1.w);
    h1[0]=f2bf(v2.x); h1[1]=f2bf(v2.y); h1[2]=f2bf(v2.z); h1[3]=f2bf(v2.w);
    h1[4]=f2bf(v3.x); h1[5]=f2bf(v3.y); h1[6]=f2bf(v3.z); h1[7]=f2bf(v3.w);
    *(short8*)(Wbf + i) = h0;
    *(short8*)(Wbf + i + 8) = h1;
}

__global__ __launch_bounds__(256) void gemm_k(
    const unsigned short* __restrict__ Abf,
    const unsigned short* __restrict__ Wbf,
    const float* __restrict__ bias, float* __restrict__ out,
    const int* __restrict__ wsi) {
    // XCD-chunked mapping: bid%8 = XCD; all 8 col-blocks of a y-tile share it.
    const int bid = blockIdx.x;
    const int c = bid & 7, j = bid >> 3;
    const int ty = (j % 17) * 8 + c;     // y-tiles interleaved across XCDs
    const int tx = j / 17;               // 0..7
    if (ty >= wsi[WI_NTILES]) return;
    const int* offs = wsi + WI_OFFS;
    const int* tab  = wsi + WI_TABLE;
    const int* ctok = wsi + WI_CTOK;
    const int e     = tab[2 * ty];
    const int crow0 = tab[2 * ty + 1];
    const int nend  = offs[e + 1];
    const int col0  = tx * BN;

    __shared__ unsigned short As[BM * BK];   // linear [row][k], 16 KB each
    __shared__ unsigned short Bs[BN * BK];

    const int tid = threadIdx.x, lane = tid & 63, wave = tid >> 6;
    const int wr = wave >> 1, wc = wave & 1;
    const int srow = tid >> 3;          // 0..31
    const int skc  = (tid & 7) * 8;     // k element offset (16B per lane)

    const unsigned short* Wb = Wbf + (size_t)e * DDIM * DDIM;

    const unsigned short* aptr[4];
    const unsigned short* bptr[4];
#pragma unroll
    for (int p = 0; p < 4; ++p) {
        int r = min(crow0 + p * 32 + srow, NTOK - 1);   // clamp tail reads
        aptr[p] = Abf + (size_t)r * DDIM + skc;
        bptr[p] = Wb + (size_t)(col0 + p * 32 + srow) * DDIM + skc;
    }

    f32x4 acc[4][4];
#pragma unroll
    for (int m = 0; m < 4; ++m)
#pragma unroll
        for (int nn = 0; nn < 4; ++nn) acc[m][nn] = (f32x4){0.f, 0.f, 0.f, 0.f};

    for (int k0 = 0; k0 < DDIM; k0 += BK) {
#pragma unroll
        for (int p = 0; p < 4; ++p)
            gload16(aptr[p] + k0, (char*)As + p * 4096 + wave * 1024);
#pragma unroll
        for (int p = 0; p < 4; ++p)
            gload16(bptr[p] + k0, (char*)Bs + p * 4096 + wave * 1024);
        __syncthreads();
#pragma unroll
        for (int ks = 0; ks < 2; ++ks) {
            const int ko = ks * 32 + (lane >> 4) * 8;
            short8 af[4], bf[4];
#pragma unroll
            for (int m = 0; m < 4; ++m)
                af[m] = *(const short8*)&As[(wr * 64 + m * 16 + (lane & 15)) * BK + ko];
#pragma unroll
            for (int nn = 0; nn < 4; ++nn)
                bf[nn] = *(const short8*)&Bs[(wc * 64 + nn * 16 + (lane & 15)) * BK + ko];
#pragma unroll
            for (int m = 0; m < 4; ++m)
#pragma unroll
                for (int nn = 0; nn < 4; ++nn)
                    acc[m][nn] = __builtin_amdgcn_mfma_f32_16x16x32_bf16(
                        af[m], bf[nn], acc[m][nn], 0, 0, 0);
        }
        __syncthreads();
    }

    const int ccol  = lane & 15;
    const int crow4 = (lane >> 4) * 4;
    float bv[4];
#pragma unroll
    for (int nn = 0; nn < 4; ++nn)
        bv[nn] = bias[e * DDIM + col0 + wc * 64 + nn * 16 + ccol];

#pragma unroll
    for (int m = 0; m < 4; ++m) {
#pragma unroll
        for (int r = 0; r < 4; ++r) {
            int gr = crow0 + wr * 64 + m * 16 + crow4 + r;
            if (gr >= nend) continue;
            int tok = ctok[gr];
            float* orow = out + (size_t)tok * DDIM + col0 + wc * 64 + ccol;
#pragma unroll
            for (int nn = 0; nn < 4; ++nn)
                orow[nn * 16] = acc[m][nn][r] + bv[nn];
        }
    }
}

extern "C" void kernel_launch(void* const* d_in, const int* in_sizes, int n_in,
                              void* d_out, int out_size, void* d_ws, size_t ws_size,
                              hipStream_t stream) {
    const float* actions = (const float*)d_in[0];
    const int*   atype   = (const int*)d_in[1];
    const float* W       = (const float*)d_in[2];
    const float* bias    = (const float*)d_in[3];
    float* out = (float*)d_out;

    int* wsi = (int*)d_ws;
    unsigned short* Abf = (unsigned short*)((char*)d_ws + WS_ABF_B);
    unsigned short* Wbf = (unsigned short*)((char*)d_ws + WS_WBF_B);

    hipMemsetAsync(d_ws, 0, 64, stream);           // counts + cursors
    count_k<<<16, 1024, 0, stream>>>(atype, wsi);
    offsets_k<<<1, 64, 0, stream>>>(wsi);
    slot_k<<<16, 1024, 0, stream>>>(atype, wsi);
    convertW_k<<<1792, 256, 0, stream>>>(W, Wbf);
    rowconv_k<<<NTOK / 4, 256, 0, stream>>>(actions, wsi, Abf, out);
    gemm_k<<<MAXTILES * 8, 256, 0, stream>>>(Abf, Wbf, bias, out, wsi);
}

// Round 5
// 93.853 us; speedup vs baseline: 5.3904x; 1.0903x over previous
//
#include <hip/hip_runtime.h>

// B=32, L=512, D=1024; 7 linear experts + identity, routed per token.
// Pipeline: [count hist + convert W->bf16] -> offsets/tile-table -> slot ->
// rowconv (gather+convert compact / identity copy) -> bf16 MFMA GEMM
// (128x128 tile, BK=64, XOR-swizzled LDS, 2-phase double-buffer,
//  XCD-chunked block mapping).

#define NTOK 16384
#define DDIM 1024
#define NEXP 7
#define BM 128
#define BN 128
#define BK 64
#define NKT (DDIM / BK)
#define MAXTILES 136          // = 8 XCDs * 17

// ws layout (int indices / byte offsets)
#define WI_COUNTS 0           // [8]
#define WI_CURS   8           // [8]
#define WI_OFFS   16          // [8]
#define WI_NTILES 32
#define WI_TABLE  64          // [136][2] {expert, crow0}
#define WI_CTOK   512         // [16384] slot -> token
#define WI_SMAP   (512 + 16384) // [16384] token -> slot (-1 = identity)
#define WS_ABF_B  1048576                       // 32 MB bf16 A (compact)
#define WS_WBF_B  (WS_ABF_B + NTOK * DDIM * 2)  // 14 MB bf16 W

typedef __attribute__((ext_vector_type(8))) short short8;
typedef __attribute__((ext_vector_type(4))) float f32x4;

__device__ __forceinline__ unsigned short f2bf(float f) {
    unsigned u = __float_as_uint(f);
    u += 0x7fff + ((u >> 16) & 1);
    return (unsigned short)(u >> 16);
}

__device__ __forceinline__ void gload16(const void* g, void* l) {
    __builtin_amdgcn_global_load_lds(
        (const __attribute__((address_space(1))) void*)g,
        (__attribute__((address_space(3))) void*)l, 16, 0, 0);
}

// blocks 0..63: LDS-histogram count; blocks 64..1855: W f32->bf16.
__global__ __launch_bounds__(256) void count_convw_k(
    const int* __restrict__ type, int* __restrict__ wsi,
    const float* __restrict__ W, unsigned short* __restrict__ Wbf) {
    __shared__ int lh[8];
    const int bid = blockIdx.x, tid = threadIdx.x;
    if (bid < 64) {
        if (tid < 8) lh[tid] = 0;
        __syncthreads();
        int k = type[bid * 256 + tid];
        if (k > 0) atomicAdd(&lh[k], 1);
        __syncthreads();
        if (tid >= 1 && tid < 8) atomicAdd(&wsi[WI_COUNTS + tid], lh[tid]);
    } else {
        size_t i = ((size_t)(bid - 64) * 256 + tid) * 16;
        const float4* src = (const float4*)(W + i);
        float4 v0 = src[0], v1 = src[1], v2 = src[2], v3 = src[3];
        short8 h0, h1;
        h0[0]=f2bf(v0.x); h0[1]=f2bf(v0.y); h0[2]=f2bf(v0.z); h0[3]=f2bf(v0.w);
        h0[4]=f2bf(v1.x); h0[5]=f2bf(v1.y); h0[6]=f2bf(v1.z); h0[7]=f2bf(v1.w);
        h1[0]=f2bf(v2.x); h1[1]=f2bf(v2.y); h1[2]=f2bf(v2.z); h1[3]=f2bf(v2.w);
        h1[4]=f2bf(v3.x); h1[5]=f2bf(v3.y); h1[6]=f2bf(v3.z); h1[7]=f2bf(v3.w);
        *(short8*)(Wbf + i) = h0;
        *(short8*)(Wbf + i + 8) = h1;
    }
}

__global__ void offsets_k(int* wsi) {
    if (threadIdx.x != 0) return;
    const int* counts = wsi + WI_COUNTS;
    int* offs  = wsi + WI_OFFS;
    int* curs  = wsi + WI_CURS;
    int* table = wsi + WI_TABLE;
    int acc = 0, t = 0;
    for (int e = 0; e < NEXP; ++e) {
        offs[e] = acc;
        curs[e + 1] = acc;
        int c = counts[e + 1];
        int nt = (c + BM - 1) / BM;
        for (int i = 0; i < nt; ++i) {
            table[2 * t] = e; table[2 * t + 1] = acc + i * BM; ++t;
        }
        acc += c;
    }
    offs[NEXP] = acc;
    wsi[WI_NTILES] = t;
}

__global__ __launch_bounds__(1024) void slot_k(
    const int* __restrict__ type, int* __restrict__ wsi) {
    __shared__ int lh[8], lbase[8];
    int tid = threadIdx.x;
    if (tid < 8) lh[tid] = 0;
    __syncthreads();
    int t = blockIdx.x * 1024 + tid;
    int k = type[t];
    int lpos = 0;
    if (k > 0) lpos = atomicAdd(&lh[k], 1);
    __syncthreads();
    if (tid >= 1 && tid < 8) lbase[tid] = atomicAdd(&wsi[WI_CURS + tid], lh[tid]);
    __syncthreads();
    int s = -1;
    if (k > 0) { s = lbase[k] + lpos; wsi[WI_CTOK + s] = t; }
    wsi[WI_SMAP + t] = s;
}

// One wave per token row: identity copy (f32->out) or gather+convert (bf16->Abf).
__global__ __launch_bounds__(256) void rowconv_k(
    const float* __restrict__ A, const int* __restrict__ wsi,
    unsigned short* __restrict__ Abf, float* __restrict__ out) {
    int wave = threadIdx.x >> 6, lane = threadIdx.x & 63;
    int t = blockIdx.x * 4 + wave;
    int s = wsi[WI_SMAP + t];
    const float4* src = (const float4*)(A + (size_t)t * DDIM);
    if (s < 0) {
        float4* d = (float4*)(out + (size_t)t * DDIM);
#pragma unroll
        for (int j = 0; j < 4; ++j) d[lane + j * 64] = src[lane + j * 64];
    } else {
        float4 v0 = src[lane * 4 + 0], v1 = src[lane * 4 + 1];
        float4 v2 = src[lane * 4 + 2], v3 = src[lane * 4 + 3];
        short8 h0, h1;
        h0[0]=f2bf(v0.x); h0[1]=f2bf(v0.y); h0[2]=f2bf(v0.z); h0[3]=f2bf(v0.w);
        h0[4]=f2bf(v1.x); h0[5]=f2bf(v1.y); h0[6]=f2bf(v1.z); h0[7]=f2bf(v1.w);
        h1[0]=f2bf(v2.x); h1[1]=f2bf(v2.y); h1[2]=f2bf(v2.z); h1[3]=f2bf(v2.w);
        h1[4]=f2bf(v3.x); h1[5]=f2bf(v3.y); h1[6]=f2bf(v3.z); h1[7]=f2bf(v3.w);
        unsigned short* d = Abf + (size_t)s * DDIM + lane * 16;
        *(short8*)d = h0;
        *(short8*)(d + 8) = h1;
    }
}

__global__ __launch_bounds__(256) void gemm_k(
    const unsigned short* __restrict__ Abf,
    const unsigned short* __restrict__ Wbf,
    const float* __restrict__ bias, float* __restrict__ out,
    const int* __restrict__ wsi) {
    // XCD-chunked mapping: bid%8 = XCD; all 8 col-blocks of a y-tile share it.
    const int bid = blockIdx.x;
    const int c = bid & 7, j = bid >> 3;
    const int ty = (j % 17) * 8 + c;
    const int tx = j / 17;
    if (ty >= wsi[WI_NTILES]) return;
    const int* offs = wsi + WI_OFFS;
    const int* tab  = wsi + WI_TABLE;
    const int* ctok = wsi + WI_CTOK;
    const int e     = tab[2 * ty];
    const int crow0 = tab[2 * ty + 1];
    const int nend  = offs[e + 1];
    const int col0  = tx * BN;

    // double-buffered, XOR-swizzled: LDS[r][s] holds global chunk s^(r&7)
    // (chunk = 16B = 8 bf16; row = 8 chunks = 128 B)
    __shared__ unsigned short As[2][BM * BK];   // 16 KB each
    __shared__ unsigned short Bs[2][BM * BK];

    const int tid = threadIdx.x, lane = tid & 63, wave = tid >> 6;
    const int wr = wave >> 1, wc = wave & 1;
    const int srow = tid >> 3;                       // 0..31
    const int swz  = ((tid & 7) ^ (srow & 7)) * 8;   // inverse-swizzled src chunk

    const unsigned short* Wb = Wbf + (size_t)e * DDIM * DDIM;
    const unsigned short* aptr[4];
    const unsigned short* bptr[4];
#pragma unroll
    for (int p = 0; p < 4; ++p) {
        int r = min(crow0 + p * 32 + srow, NTOK - 1);   // clamp tail reads
        aptr[p] = Abf + (size_t)r * DDIM + swz;
        bptr[p] = Wb + (size_t)(col0 + p * 32 + srow) * DDIM + swz;
    }

    f32x4 acc[4][4];
#pragma unroll
    for (int m = 0; m < 4; ++m)
#pragma unroll
        for (int nn = 0; nn < 4; ++nn) acc[m][nn] = (f32x4){0.f, 0.f, 0.f, 0.f};

    // prologue: stage K-tile 0 into buf 0
#pragma unroll
    for (int p = 0; p < 4; ++p)
        gload16(aptr[p], (char*)As[0] + p * 4096 + wave * 1024);
#pragma unroll
    for (int p = 0; p < 4; ++p)
        gload16(bptr[p], (char*)Bs[0] + p * 4096 + wave * 1024);
    __syncthreads();

    for (int kt = 0; kt < NKT; ++kt) {
        const int cur = kt & 1;
        if (kt + 1 < NKT) {   // issue next tile's loads into the other buffer
            const int k1 = (kt + 1) * BK;
#pragma unroll
            for (int p = 0; p < 4; ++p)
                gload16(aptr[p] + k1, (char*)As[cur ^ 1] + p * 4096 + wave * 1024);
#pragma unroll
            for (int p = 0; p < 4; ++p)
                gload16(bptr[p] + k1, (char*)Bs[cur ^ 1] + p * 4096 + wave * 1024);
        }
#pragma unroll
        for (int ks = 0; ks < 2; ++ks) {
            const int cbase = ks * 4 + (lane >> 4);          // k-chunk 0..7
            const int sl = ((cbase ^ (lane & 7))) * 8;       // swizzled slot
            short8 af[4], bf[4];
#pragma unroll
            for (int m = 0; m < 4; ++m)
                af[m] = *(const short8*)&As[cur][(wr * 64 + m * 16 + (lane & 15)) * BK + sl];
#pragma unroll
            for (int nn = 0; nn < 4; ++nn)
                bf[nn] = *(const short8*)&Bs[cur][(wc * 64 + nn * 16 + (lane & 15)) * BK + sl];
#pragma unroll
            for (int m = 0; m < 4; ++m)
#pragma unroll
                for (int nn = 0; nn < 4; ++nn)
                    acc[m][nn] = __builtin_amdgcn_mfma_f32_16x16x32_bf16(
                        af[m], bf[nn], acc[m][nn], 0, 0, 0);
        }
        __syncthreads();   // vmcnt(0): next buf landed; all reads of cur done
    }

    const int ccol  = lane & 15;
    const int crow4 = (lane >> 4) * 4;
    float bv[4];
#pragma unroll
    for (int nn = 0; nn < 4; ++nn)
        bv[nn] = bias[e * DDIM + col0 + wc * 64 + nn * 16 + ccol];

#pragma unroll
    for (int m = 0; m < 4; ++m) {
#pragma unroll
        for (int r = 0; r < 4; ++r) {
            int gr = crow0 + wr * 64 + m * 16 + crow4 + r;
            if (gr >= nend) continue;
            int tok = ctok[gr];
            float* orow = out + (size_t)tok * DDIM + col0 + wc * 64 + ccol;
#pragma unroll
            for (int nn = 0; nn < 4; ++nn)
                orow[nn * 16] = acc[m][nn][r] + bv[nn];
        }
    }
}

extern "C" void kernel_launch(void* const* d_in, const int* in_sizes, int n_in,
                              void* d_out, int out_size, void* d_ws, size_t ws_size,
                              hipStream_t stream) {
    const float* actions = (const float*)d_in[0];
    const int*   atype   = (const int*)d_in[1];
    const float* W       = (const float*)d_in[2];
    const float* bias    = (const float*)d_in[3];
    float* out = (float*)d_out;

    int* wsi = (int*)d_ws;
    unsigned short* Abf = (unsigned short*)((char*)d_ws + WS_ABF_B);
    unsigned short* Wbf = (unsigned short*)((char*)d_ws + WS_WBF_B);

    hipMemsetAsync(d_ws, 0, 64, stream);              // counts + cursors
    count_convw_k<<<64 + 1792, 256, 0, stream>>>(atype, wsi, W, Wbf);
    offsets_k<<<1, 64, 0, stream>>>(wsi);
    slot_k<<<16, 1024, 0, stream>>>(atype, wsi);
    rowconv_k<<<NTOK / 4, 256, 0, stream>>>(actions, wsi, Abf, out);
    gemm_k<<<MAXTILES * 8, 256, 0, stream>>>(Abf, Wbf, bias, out, wsi);
}